// Round 5
// baseline (176.803 us; speedup 1.0000x reference)
//
#include <hip/hip_runtime.h>
#include <hip/hip_bf16.h>

typedef __bf16 bf16x8 __attribute__((ext_vector_type(8)));
typedef float  f32x4  __attribute__((ext_vector_type(4)));

#define NEG_BIG (-1e10f)

constexpr int FUSED_N = 4 * 32 * 32 * 256;  // 1048576

// ---------------------------------------------------------------------------
// fp32 inputs, no fp32 MFMA on CDNA4: split x = hi + lo (bf16 RNE + residual),
// scores ~= Ah*Bh + Ah*Bl + Al*Bh (drop lo*lo, ~2^-18 rel). Verified r2-r4.
// r3 lesson: VGPR budget 64 -> scratch spill (+54 MB WRITE_SIZE).
// r4 lesson: fusing W fp32->bf16 split into prep's inner loop made prep
//            VALU-bound (~60 us). Convert W ONCE in a tiny kernel.
// ---------------------------------------------------------------------------

// 16B-granule XOR swizzle for a 64row x 16granule (64x128 bf16) chunk.
__device__ __forceinline__ int swz16(int row, int g) {
    return (row * 16 + (g ^ (row & 15))) * 8;
}
// 16row x 32granule (16x256 bf16) tile for prep.
__device__ __forceinline__ int swzp(int row, int g) {
    return (row * 32 + (g ^ row)) * 8;   // row in [0,16)
}

// Async 16B global->LDS (DMA). Lane L lands at wave-uniform base + 16*L.
__device__ __forceinline__ void async_ld16(const void* g, void* l) {
    __builtin_amdgcn_global_load_lds(
        (const __attribute__((address_space(1))) void*)g,
        (__attribute__((address_space(3))) void*)l, 16, 0, 0);
}

// W fp32 -> hi/lo bf16 planes. 64 blocks x 256 threads x 4 elems.
__global__ __launch_bounds__(256) void convw_kernel(
    const float* __restrict__ W, __bf16* __restrict__ Wh, __bf16* __restrict__ Wl) {
    int idx = blockIdx.x * 256 + threadIdx.x;  // 0..16383
    float4 v = ((const float4*)W)[idx];
    float f[4] = {v.x, v.y, v.z, v.w};
    union { __bf16 b[4]; uint2 u; } H, L;
#pragma unroll
    for (int k = 0; k < 4; ++k) {
        __bf16 h = (__bf16)f[k];
        H.b[k] = h;
        L.b[k] = (__bf16)(f[k] - (float)h);
    }
    *(uint2*)&Wh[idx * 4] = H.u;
    *(uint2*)&Wl[idx * 4] = L.u;
}

// ---------------------------------------------------------------------------
// prep: convert 16 X rows -> Xh/Xl planes (global + LDS) and compute
// P = X @ W^T (split-3) -> Ph/Pl. 512 blocks; wave w handles col group w.
// B-fragments stream from L2-hot bf16 W planes (no per-block conversion).
// ---------------------------------------------------------------------------
__global__ __launch_bounds__(256, 2) void prep_kernel(
    const float* __restrict__ Xf,
    const __bf16* __restrict__ Wh, const __bf16* __restrict__ Wl,
    __bf16* __restrict__ XhG, __bf16* __restrict__ XlG,
    __bf16* __restrict__ Ph, __bf16* __restrict__ Pl) {
    __shared__ __align__(16) __bf16 sXh[16 * 256];   // 8 KB
    __shared__ __align__(16) __bf16 sXl[16 * 256];   // 8 KB
    const int tid = threadIdx.x, rb = blockIdx.x;    // rows rb*16..rb*16+15

#pragma unroll
    for (int it = 0; it < 2; ++it) {
        int idx = it * 256 + tid;          // 512 granules
        int row = idx >> 5, g = idx & 31;
        const float* p = Xf + (rb * 16 + row) * 256 + g * 8;
        float4 v0 = *(const float4*)p;
        float4 v1 = *(const float4*)(p + 4);
        float f[8] = {v0.x, v0.y, v0.z, v0.w, v1.x, v1.y, v1.z, v1.w};
        union { __bf16 b[8]; uint4 u; } H, L;
#pragma unroll
        for (int k = 0; k < 8; ++k) {
            __bf16 h = (__bf16)f[k];
            H.b[k] = h;
            L.b[k] = (__bf16)(f[k] - (float)h);
        }
        int go = (rb * 16 + row) * 256 + g * 8;
        *(uint4*)&XhG[go] = H.u;
        *(uint4*)&XlG[go] = L.u;
        int o = swzp(row, g);
        *(uint4*)&sXh[o] = H.u;
        *(uint4*)&sXl[o] = L.u;
    }
    __syncthreads();

    const int lane = tid & 63, wave = tid >> 6, m = lane & 15, quad = lane >> 4;
    bf16x8 Ah[8], Al[8];
#pragma unroll
    for (int k0 = 0; k0 < 8; ++k0) {
        int o = swzp(m, k0 * 4 + quad);
        Ah[k0] = *(const bf16x8*)&sXh[o];
        Al[k0] = *(const bf16x8*)&sXl[o];
    }
    f32x4 acc[4];
    const f32x4 z = {0.f, 0.f, 0.f, 0.f};
#pragma unroll
    for (int n = 0; n < 4; ++n) acc[n] = z;
#pragma unroll
    for (int k0 = 0; k0 < 8; ++k0) {
#pragma unroll
        for (int n = 0; n < 4; ++n) {
            const int gcol = wave * 64 + n * 16 + m;
            const int wo = gcol * 256 + k0 * 32 + quad * 8;
            bf16x8 bh = *(const bf16x8*)&Wh[wo];
            bf16x8 bl = *(const bf16x8*)&Wl[wo];
            acc[n] = __builtin_amdgcn_mfma_f32_16x16x32_bf16(Ah[k0], bh, acc[n], 0, 0, 0);
            acc[n] = __builtin_amdgcn_mfma_f32_16x16x32_bf16(Ah[k0], bl, acc[n], 0, 0, 0);
            acc[n] = __builtin_amdgcn_mfma_f32_16x16x32_bf16(Al[k0], bh, acc[n], 0, 0, 0);
        }
    }
#pragma unroll
    for (int n = 0; n < 4; ++n)
#pragma unroll
        for (int r = 0; r < 4; ++r) {
            int row = rb * 16 + quad * 4 + r;
            int col = wave * 64 + n * 16 + m;
            float v = acc[n][r];
            __bf16 h = (__bf16)v;
            Ph[row * 256 + col] = h;
            Pl[row * 256 + col] = (__bf16)(v - (float)h);
        }
}

// ---------------------------------------------------------------------------
// main: one block per (b,i,j-pair). P(b,i) fragments in registers; X(b,j)
// hi/lo staged per K=128 chunk via async global_load_lds (swizzle-inverted
// gather). 34 KB LDS, (256,4) -> 4 blocks/CU. j1's first DMA overlaps j0's
// epilogue.
// ---------------------------------------------------------------------------
__global__ __launch_bounds__(256, 4) void main_kernel(
    const float* __restrict__ Xf, const float* __restrict__ maskf,
    const float* __restrict__ aselff,
    const __bf16* __restrict__ XhG, const __bf16* __restrict__ XlG,
    const __bf16* __restrict__ Ph, const __bf16* __restrict__ Pl,
    float* __restrict__ out) {
    __shared__ __align__(16) __bf16 sXh[64 * 128];   // 16 KB
    __shared__ __align__(16) __bf16 sXl[64 * 128];   // 16 KB
    __shared__ float sWpart[4 * 64];                 // 1 KB
    __shared__ float s_w[64];
    const int tid = threadIdx.x;
    const int jp = blockIdx.x & 15;
    const int i = (blockIdx.x >> 4) & 31;
    const int b = blockIdx.x >> 9;
    const int lane = tid & 63, wave = tid >> 6, m = lane & 15, quad = lane >> 4;
    const int xb0 = (b * 32 + jp * 2) * 16384;
    const int xb1 = xb0 + 16384;

    // Async stage of one K=128 chunk (hi+lo). Wave w: insts ii=4w..4w+3,
    // inst ii covers row ii*4+quad; lane slot m holds granule m^(row&15).
    auto stage = [&](int xbase, int kc) {
#pragma unroll
        for (int it = 0; it < 4; ++it) {
            const int ii = wave * 4 + it;
            const int row = ii * 4 + quad;
            const int g = m ^ (row & 15);
            const int go = xbase + row * 256 + kc * 128 + g * 8;
            async_ld16(&XhG[go], &sXh[ii * 512]);
            async_ld16(&XlG[go], &sXl[ii * 512]);
        }
    };

    stage(xb0, 0);  // DMA in flight while A-frags load

    // A fragments: P rows wave*16+m, full K=256, hi/lo (64 VGPRs).
    const int prow = ((b * 32 + i) * 64 + wave * 16 + m) * 256;
    bf16x8 Ah[8], Al[8];
#pragma unroll
    for (int k0 = 0; k0 < 8; ++k0) {
        Ah[k0] = *(const bf16x8*)&Ph[prow + k0 * 32 + quad * 8];
        Al[k0] = *(const bf16x8*)&Pl[prow + k0 * 32 + quad * 8];
    }
    const float4 aself4 = *(const float4*)&aselff[(b * 32 + i) * 64 + wave * 16 + quad * 4];
    float madd[2][4];
#pragma unroll
    for (int jt = 0; jt < 2; ++jt) {
        const float* mrow = maskf + (b * 32 + jp * 2 + jt) * 64;
#pragma unroll
        for (int n = 0; n < 4; ++n) madd[jt][n] = (1.0f - mrow[n * 16 + m]) * NEG_BIG;
    }

    const f32x4 z = {0.f, 0.f, 0.f, 0.f};
    f32x4 acc[4];

    auto mfma_chunk = [&](int kc) {
#pragma unroll
        for (int k0 = 0; k0 < 4; ++k0) {
            const int ak = kc * 4 + k0;
#pragma unroll
            for (int n = 0; n < 4; ++n) {
                const int bo = swz16(n * 16 + m, k0 * 4 + quad);
                bf16x8 bh = *(const bf16x8*)&sXh[bo];
                bf16x8 bl = *(const bf16x8*)&sXl[bo];
                acc[n] = __builtin_amdgcn_mfma_f32_16x16x32_bf16(Ah[ak], bh, acc[n], 0, 0, 0);
                acc[n] = __builtin_amdgcn_mfma_f32_16x16x32_bf16(Ah[ak], bl, acc[n], 0, 0, 0);
                acc[n] = __builtin_amdgcn_mfma_f32_16x16x32_bf16(Al[ak], bh, acc[n], 0, 0, 0);
            }
        }
    };

    // Epilogue: sigmoid -> att; w[t] = sum_s aself[s]*att[s,t]; fused.
    // Optionally issues next j's chunk-0 DMA after the barrier that retires
    // this j's chunk-1 LDS reads (overlaps DMA with reduction + fused loop).
    auto epilogue = [&](int jt, int xbase, bool prefetch, int xnext) {
        const int j = jp * 2 + jt;
        float* outA = out + FUSED_N + ((size_t)((b * 32 + i) * 32 + j)) * 4096;
        float part[4];
#pragma unroll
        for (int n = 0; n < 4; ++n) {
            const int t = n * 16 + m;
            float p = 0.f;
#pragma unroll
            for (int r = 0; r < 4; ++r) {
                const int s = wave * 16 + quad * 4 + r;
                float x = acc[n][r] + madd[jt][n];
                float a = 1.0f / (1.0f + __expf(-x));
                outA[s * 64 + t] = a;
                p += ((const float*)&aself4)[r] * a;
            }
            part[n] = p;
        }
#pragma unroll
        for (int n = 0; n < 4; ++n) {   // reduce over quad
            part[n] += __shfl_xor(part[n], 16, 64);
            part[n] += __shfl_xor(part[n], 32, 64);
        }
        if (quad == 0) {
#pragma unroll
            for (int n = 0; n < 4; ++n) sWpart[wave * 64 + n * 16 + m] = part[n];
        }
        __syncthreads();                 // sWpart visible + chunk1 reads done
        if (prefetch) stage(xnext, 0);
        if (tid < 64)
            s_w[tid] = sWpart[tid] + sWpart[64 + tid] + sWpart[128 + tid] + sWpart[192 + tid];
        __syncthreads();                 // s_w visible (+ drains DMA)
        const float* Xg = Xf + xbase;
        float acf = 0.f;
#pragma unroll 8
        for (int t = 0; t < 64; ++t) acf += s_w[t] * Xg[t * 256 + tid];
        out[((size_t)((b * 32 + i) * 32 + j)) * 256 + tid] = acf;
    };

    // ---- j0 ----
#pragma unroll
    for (int n = 0; n < 4; ++n) acc[n] = z;
    __syncthreads();         // chunk0 DMA drained
    mfma_chunk(0);
    __syncthreads();         // chunk0 LDS reads done
    stage(xb0, 1);
    __syncthreads();         // chunk1 DMA drained
    mfma_chunk(1);
    epilogue(0, xb0, true, xb1);   // issues stage(xb1, 0) mid-epilogue

    // ---- j1 ----
#pragma unroll
    for (int n = 0; n < 4; ++n) acc[n] = z;
    mfma_chunk(0);           // DMA was drained by epilogue's 2nd barrier
    __syncthreads();
    stage(xb1, 1);
    __syncthreads();
    mfma_chunk(1);
    epilogue(1, xb1, false, 0);
}

extern "C" void kernel_launch(void* const* d_in, const int* in_sizes, int n_in,
                              void* d_out, int out_size, void* d_ws, size_t ws_size,
                              hipStream_t stream) {
    const float* X     = (const float*)d_in[0];  // [4,32,64,256] fp32
    const float* mask  = (const float*)d_in[1];  // [4,32,64]
    const float* aself = (const float*)d_in[2];  // [4,32,64]
    const float* W     = (const float*)d_in[3];  // [256,256]
    float* out = (float*)d_out;

    __bf16* ws = (__bf16*)d_ws;
    const size_t NX = 2097152, NW = 65536;
    __bf16* Xh = ws;
    __bf16* Xl = Xh + NX;
    __bf16* Ph = Xl + NX;
    __bf16* Pl = Ph + NX;
    __bf16* Wh = Pl + NX;
    __bf16* Wl = Wh + NW;

    convw_kernel<<<dim3(64), dim3(256), 0, stream>>>(W, Wh, Wl);
    prep_kernel<<<dim3(512), dim3(256), 0, stream>>>(X, Wh, Wl, Xh, Xl, Ph, Pl);
    main_kernel<<<dim3(2048), dim3(256), 0, stream>>>(
        X, mask, aself, Xh, Xl, Ph, Pl, out);
}

// Round 7
// 149.307 us; speedup vs baseline: 1.1842x; 1.1842x over previous
//
#include <hip/hip_runtime.h>
#include <hip/hip_bf16.h>

typedef __bf16 bf16x8 __attribute__((ext_vector_type(8)));
typedef float  f32x4  __attribute__((ext_vector_type(4)));

#define NEG_BIG (-1e10f)

constexpr int FUSED_N = 4 * 32 * 32 * 256;  // 1048576

// ---------------------------------------------------------------------------
// fp32 inputs, no fp32 MFMA on CDNA4: split x = hi + lo (bf16 RNE + residual),
// scores ~= Ah*Bh + Ah*Bl + Al*Bh (drop lo*lo). Verified r2-r5.
// r3/r5 lesson: VGPR pressure -> scratch spill shows as WRITE_SIZE above the
//   exact 69,636 KB floor (att 64 MB + fused 4 MB). That's the tripwire.
// r5 lesson: total-minus-main ~90 us is fixed harness overhead; only
//   main_kernel is controllable.
// r6 lesson: staging loop issued 64 insts (2 rows each) for a 64-row tile ->
//   LDS overflow + neighbor-tile reads. Each async_ld16 covers 2 rows; 64
//   rows = 32 insts = 8 per wave. FIXED here (it < 8).
// ---------------------------------------------------------------------------

// Async 16B global->LDS (DMA). Lane L lands at wave-uniform base + 16*L.
__device__ __forceinline__ void async_ld16(const void* g, void* l) {
    __builtin_amdgcn_global_load_lds(
        (const __attribute__((address_space(1))) void*)g,
        (__attribute__((address_space(3))) void*)l, 16, 0, 0);
}

// 16row x 32granule (16x256 bf16) tile for prep.
__device__ __forceinline__ int swzp(int row, int g) {
    return (row * 32 + (g ^ row)) * 8;   // row in [0,16)
}

// W fp32 -> hi/lo bf16 planes. 64 blocks x 256 threads x 4 elems.
__global__ __launch_bounds__(256) void convw_kernel(
    const float* __restrict__ W, __bf16* __restrict__ Wh, __bf16* __restrict__ Wl) {
    int idx = blockIdx.x * 256 + threadIdx.x;  // 0..16383
    float4 v = ((const float4*)W)[idx];
    float f[4] = {v.x, v.y, v.z, v.w};
    union { __bf16 b[4]; uint2 u; } H, L;
#pragma unroll
    for (int k = 0; k < 4; ++k) {
        __bf16 h = (__bf16)f[k];
        H.b[k] = h;
        L.b[k] = (__bf16)(f[k] - (float)h);
    }
    *(uint2*)&Wh[idx * 4] = H.u;
    *(uint2*)&Wl[idx * 4] = L.u;
}

// ---------------------------------------------------------------------------
// prep: convert 16 X rows -> Xh/Xl planes (global + LDS) and compute
// P = X @ W^T (split-3) -> Ph/Pl. 512 blocks; wave w handles col group w.
// ---------------------------------------------------------------------------
__global__ __launch_bounds__(256, 2) void prep_kernel(
    const float* __restrict__ Xf,
    const __bf16* __restrict__ Wh, const __bf16* __restrict__ Wl,
    __bf16* __restrict__ XhG, __bf16* __restrict__ XlG,
    __bf16* __restrict__ Ph, __bf16* __restrict__ Pl) {
    __shared__ __align__(16) __bf16 sXh[16 * 256];   // 8 KB
    __shared__ __align__(16) __bf16 sXl[16 * 256];   // 8 KB
    const int tid = threadIdx.x, rb = blockIdx.x;    // rows rb*16..rb*16+15

#pragma unroll
    for (int it = 0; it < 2; ++it) {
        int idx = it * 256 + tid;          // 512 granules
        int row = idx >> 5, g = idx & 31;
        const float* p = Xf + (rb * 16 + row) * 256 + g * 8;
        float4 v0 = *(const float4*)p;
        float4 v1 = *(const float4*)(p + 4);
        float f[8] = {v0.x, v0.y, v0.z, v0.w, v1.x, v1.y, v1.z, v1.w};
        union { __bf16 b[8]; uint4 u; } H, L;
#pragma unroll
        for (int k = 0; k < 8; ++k) {
            __bf16 h = (__bf16)f[k];
            H.b[k] = h;
            L.b[k] = (__bf16)(f[k] - (float)h);
        }
        int go = (rb * 16 + row) * 256 + g * 8;
        *(uint4*)&XhG[go] = H.u;
        *(uint4*)&XlG[go] = L.u;
        int o = swzp(row, g);
        *(uint4*)&sXh[o] = H.u;
        *(uint4*)&sXl[o] = L.u;
    }
    __syncthreads();

    const int lane = tid & 63, wave = tid >> 6, m = lane & 15, quad = lane >> 4;
    bf16x8 Ah[8], Al[8];
#pragma unroll
    for (int k0 = 0; k0 < 8; ++k0) {
        int o = swzp(m, k0 * 4 + quad);
        Ah[k0] = *(const bf16x8*)&sXh[o];
        Al[k0] = *(const bf16x8*)&sXl[o];
    }
    f32x4 acc[4];
    const f32x4 z = {0.f, 0.f, 0.f, 0.f};
#pragma unroll
    for (int n = 0; n < 4; ++n) acc[n] = z;
#pragma unroll
    for (int k0 = 0; k0 < 8; ++k0) {
#pragma unroll
        for (int n = 0; n < 4; ++n) {
            const int gcol = wave * 64 + n * 16 + m;
            const int wo = gcol * 256 + k0 * 32 + quad * 8;
            bf16x8 bh = *(const bf16x8*)&Wh[wo];
            bf16x8 bl = *(const bf16x8*)&Wl[wo];
            acc[n] = __builtin_amdgcn_mfma_f32_16x16x32_bf16(Ah[k0], bh, acc[n], 0, 0, 0);
            acc[n] = __builtin_amdgcn_mfma_f32_16x16x32_bf16(Ah[k0], bl, acc[n], 0, 0, 0);
            acc[n] = __builtin_amdgcn_mfma_f32_16x16x32_bf16(Al[k0], bh, acc[n], 0, 0, 0);
        }
    }
#pragma unroll
    for (int n = 0; n < 4; ++n)
#pragma unroll
        for (int r = 0; r < 4; ++r) {
            int row = rb * 16 + quad * 4 + r;
            int col = wave * 64 + n * 16 + m;
            float v = acc[n][r];
            __bf16 h = (__bf16)v;
            Ph[row * 256 + col] = h;
            Pl[row * 256 + col] = (__bf16)(v - (float)h);
        }
}

// ---------------------------------------------------------------------------
// main: 512 blocks = (b, i, jq). Stage P(b,i) hi/lo (64 KB, swizzled) via
// async DMA; ONE barrier; then each wave independently computes full 64x64
// score tiles for j = jq*8 + jt*4 + wave (jt=0,1), streaming X hi/lo
// fragments from global (L2-hot). Epilogue (sigmoid, att store, w-reduce,
// fused) is wave-local: quad shuffles + wave-private LDS row, no barriers.
// ---------------------------------------------------------------------------
__global__ __launch_bounds__(256, 2) void main_kernel(
    const float* __restrict__ Xf, const float* __restrict__ maskf,
    const float* __restrict__ aselff,
    const __bf16* __restrict__ XhG, const __bf16* __restrict__ XlG,
    const __bf16* __restrict__ PhG, const __bf16* __restrict__ PlG,
    float* __restrict__ out) {
    __shared__ __align__(16) __bf16 sPh[64 * 256];   // 32 KB
    __shared__ __align__(16) __bf16 sPl[64 * 256];   // 32 KB
    __shared__ float sW[4][64];                      // 1 KB, wave-private rows
    const int tid = threadIdx.x;
    const int jq = blockIdx.x & 3;
    const int i  = (blockIdx.x >> 2) & 31;
    const int b  = blockIdx.x >> 7;
    const int lane = tid & 63, wave = tid >> 6, m = lane & 15, quad = lane >> 4;

    // Stage P(b,i) hi/lo. Each inst covers rows 2*insti..+1 (64 lanes x 16B);
    // 64 rows = 32 insts = 8 per wave. Slot (row,gs) gets granule gs^(row&15).
    const int pbase = (b * 32 + i) * 16384;
    {
        const int rowhalf = lane >> 5;     // 0..1
        const int gslot = lane & 31;
#pragma unroll
        for (int it = 0; it < 8; ++it) {
            const int insti = wave * 8 + it;           // 0..31
            const int row = insti * 2 + rowhalf;       // 0..63
            const int g = gslot ^ (row & 15);
            const int src = pbase + row * 256 + g * 8;
            async_ld16(&PhG[src], &sPh[insti * 512]);
            async_ld16(&PlG[src], &sPl[insti * 512]);
        }
    }

    // aself for this lane's 16 s-slots (rg x r); i is block-constant.
    const float* ap = aselff + (b * 32 + i) * 64;
    float4 asv[4];
#pragma unroll
    for (int rg = 0; rg < 4; ++rg)
        asv[rg] = *(const float4*)&ap[rg * 16 + quad * 4];

    __syncthreads();   // DMA drained; the ONLY barrier

    for (int jt = 0; jt < 2; ++jt) {
        const int j = jq * 8 + jt * 4 + wave;
        const int xb = (b * 32 + j) * 16384;

        f32x4 acc[4][4];
        const f32x4 z = {0.f, 0.f, 0.f, 0.f};
#pragma unroll
        for (int rg = 0; rg < 4; ++rg)
#pragma unroll
            for (int ng = 0; ng < 4; ++ng) acc[rg][ng] = z;

#pragma unroll
        for (int k0 = 0; k0 < 8; ++k0) {
            bf16x8 Bh[4], Bl[4];
#pragma unroll
            for (int ng = 0; ng < 4; ++ng) {
                const int bo = xb + (ng * 16 + m) * 256 + k0 * 32 + quad * 8;
                Bh[ng] = *(const bf16x8*)&XhG[bo];
                Bl[ng] = *(const bf16x8*)&XlG[bo];
            }
            bf16x8 Ahk[4], Alk[4];
#pragma unroll
            for (int rg = 0; rg < 4; ++rg) {
                const int o = (rg * 16 + m) * 256 + (((k0 * 4 + quad) ^ m)) * 8;
                Ahk[rg] = *(const bf16x8*)&sPh[o];
                Alk[rg] = *(const bf16x8*)&sPl[o];
            }
#pragma unroll
            for (int rg = 0; rg < 4; ++rg)
#pragma unroll
                for (int ng = 0; ng < 4; ++ng) {
                    acc[rg][ng] = __builtin_amdgcn_mfma_f32_16x16x32_bf16(Ahk[rg], Bh[ng], acc[rg][ng], 0, 0, 0);
                    acc[rg][ng] = __builtin_amdgcn_mfma_f32_16x16x32_bf16(Ahk[rg], Bl[ng], acc[rg][ng], 0, 0, 0);
                    acc[rg][ng] = __builtin_amdgcn_mfma_f32_16x16x32_bf16(Alk[rg], Bh[ng], acc[rg][ng], 0, 0, 0);
                }
        }

        // ---- wave-local epilogue ----
        const float* mrow = maskf + (b * 32 + j) * 64;
        float madd[4];
#pragma unroll
        for (int ng = 0; ng < 4; ++ng)
            madd[ng] = (1.0f - mrow[ng * 16 + m]) * NEG_BIG;

        float part[4] = {0.f, 0.f, 0.f, 0.f};
        float* outA = out + FUSED_N + ((size_t)((b * 32 + i) * 32 + j)) * 4096;
#pragma unroll
        for (int rg = 0; rg < 4; ++rg)
#pragma unroll
            for (int r = 0; r < 4; ++r) {
                const int s = rg * 16 + quad * 4 + r;
                const float as_ = ((const float*)&asv[rg])[r];
#pragma unroll
                for (int ng = 0; ng < 4; ++ng) {
                    float x = acc[rg][ng][r] + madd[ng];
                    float a = 1.0f / (1.0f + __expf(-x));
                    outA[s * 64 + ng * 16 + m] = a;
                    part[ng] += as_ * a;
                }
            }
#pragma unroll
        for (int ng = 0; ng < 4; ++ng) {   // reduce over quad (t = ng*16+m)
            part[ng] += __shfl_xor(part[ng], 16, 64);
            part[ng] += __shfl_xor(part[ng], 32, 64);
        }
        if (quad == 0) {
#pragma unroll
            for (int ng = 0; ng < 4; ++ng) sW[wave][ng * 16 + m] = part[ng];
        }
        // Within-wave LDS write->read: in-order, lgkmcnt-protected; no barrier.
        const float* Xg = Xf + xb;
        float4 acf = {0.f, 0.f, 0.f, 0.f};
#pragma unroll 8
        for (int t = 0; t < 64; ++t) {
            const float wv = sW[wave][t];
            float4 xv = *(const float4*)&Xg[t * 256 + lane * 4];
            acf.x += wv * xv.x;
            acf.y += wv * xv.y;
            acf.z += wv * xv.z;
            acf.w += wv * xv.w;
        }
        *(float4*)&out[((size_t)((b * 32 + i) * 32 + j)) * 256 + lane * 4] = acf;
    }
}

extern "C" void kernel_launch(void* const* d_in, const int* in_sizes, int n_in,
                              void* d_out, int out_size, void* d_ws, size_t ws_size,
                              hipStream_t stream) {
    const float* X     = (const float*)d_in[0];  // [4,32,64,256] fp32
    const float* mask  = (const float*)d_in[1];  // [4,32,64]
    const float* aself = (const float*)d_in[2];  // [4,32,64]
    const float* W     = (const float*)d_in[3];  // [256,256]
    float* out = (float*)d_out;

    __bf16* ws = (__bf16*)d_ws;
    const size_t NX = 2097152, NW = 65536;
    __bf16* Xh = ws;
    __bf16* Xl = Xh + NX;
    __bf16* Ph = Xl + NX;
    __bf16* Pl = Ph + NX;
    __bf16* Wh = Pl + NX;
    __bf16* Wl = Wh + NW;

    convw_kernel<<<dim3(64), dim3(256), 0, stream>>>(W, Wh, Wl);
    prep_kernel<<<dim3(512), dim3(256), 0, stream>>>(X, Wh, Wl, Xh, Xl, Ph, Pl);
    main_kernel<<<dim3(512), dim3(256), 0, stream>>>(
        X, mask, aself, Xh, Xl, Ph, Pl, out);
}